// Round 3
// baseline (297.233 us; speedup 1.0000x reference)
//
#include <hip/hip_runtime.h>
#include <hip/hip_fp16.h>

// ---------------------------------------------------------------------------
// 2-layer GCN. Round 12 (= r11 structure + coordinate-space fix):
//  - r11 CRASH ROOT CAUSE: off/entries1 lived in the sparse b*CAP coordinate
//    space (max ~2.4M) while entries1 was sized nE=1.6M -> OOB writes +
//    aggregates gathered H at garbage indices -> memory fault.
//    FIX: regroup reserves a compact entries1 region per bucket via global
//    cursor atomicAdd (sum of btot == nE, so all pos < nE). Regions are
//    contiguous-but-unordered; all consumers go through off[]/deg[].
//  - aggregate fetch proven AT compulsory-replication floor (90.4MB ~=
//    8 XCD x 12.8MB x 86.5% line coverage); PRESCALED A/B was flat ->
//    pure fill-bound. agg_node body untouched.
//  - build_scatter: one kernel (count -> reserve region -> scatter),
//    fixed-capacity entries0 regions (CAP=3072/bucket, 23-sigma margin).
//  - agg1+gemm2 fused: block = 64 nodes (4 waves x 16), aggregate (+b1+self)
//    lands fp32 in xt LDS, then in-block 64x64x64 GEMM with W2 + dinv
//    row-prescale -> H2 fp16. Kills A1h 25.6MB round-trip.
// Dispatches: memset + 4 (build_scatter, regroup||gemm1, agg1_gemm2, agg2).
// NEVER use cooperative grid.sync on this stack (r7: ~90us/sync).
// ---------------------------------------------------------------------------

#define D 64
#define NPB 128          // nodes per bucket (dst >> 7)
#define MAXB 784         // >= ceil(100000/128) = 782 (+2 spare overflow room)
#define CHUNK 4096       // edges per build chunk
#define BT 512           // threads for build_scatter
#define CAP 3072         // entry slots per bucket (expected 2046, sigma~45)

// --- build_scatter: count chunk -> reserve per-bucket region -> scatter ----
// Edges kept in registers; one global read of src/dst total.
__global__ __launch_bounds__(BT) void build_scatter(const int* __restrict__ src,
                                                    const int* __restrict__ dst,
                                                    int* __restrict__ bcur,
                                                    int* __restrict__ entries0,
                                                    int nE, int B) {
    __shared__ int hist[MAXB];
    __shared__ int curs[MAXB];
    const int t = threadIdx.x;
    const int c = blockIdx.x;
    for (int b = t; b < B; b += BT) hist[b] = 0;
    __syncthreads();
    int e0 = c * CHUNK;
    int sv[CHUNK / BT], dv[CHUNK / BT];
#pragma unroll
    for (int i = 0; i < CHUNK / BT; ++i) {
        int e = e0 + i * BT + t;
        sv[i] = 0; dv[i] = -1;
        if (e < nE) {
            sv[i] = src[e];
            dv[i] = dst[e];
            atomicAdd(&hist[dv[i] >> 7], 1);
        }
    }
    __syncthreads();
    for (int b = t; b < B; b += BT) {
        int cnt = hist[b];
        int base = 0;
        if (cnt > 0) base = atomicAdd(&bcur[b], cnt);
        curs[b] = b * CAP + base;
    }
    __syncthreads();
#pragma unroll
    for (int i = 0; i < CHUNK / BT; ++i) {
        if (dv[i] >= 0) {
            int b = dv[i] >> 7;
            int pos = atomicAdd(&curs[b], 1);
            entries0[pos] = sv[i] | ((dv[i] & (NPB - 1)) << 17);
        }
    }
}

// --- regroup body: count+scan -> COMPACT region alloc -> node-sorted src --
// entries0 segment is sparse [s0, s1); output region in entries1 is compact,
// reserved via global cursor (sum over buckets == nE -> all pos < nE).
__device__ __forceinline__ void regroup_body(const int* __restrict__ entries0,
                                             int s0, int s1,
                                             int* __restrict__ off,
                                             int* __restrict__ deg,
                                             float* __restrict__ dinv,
                                             int* __restrict__ entries1,
                                             int* __restrict__ cursor, int N, int b,
                                             int* cnt, int* scn, int* cur, int* shb) {
    int t = threadIdx.x;
    if (t < NPB) cnt[t] = 0;
    if (t == 0) *shb = atomicAdd(cursor, s1 - s0);   // compact bucket base
    __syncthreads();
    for (int p = s0 + t; p < s1; p += 256)
        atomicAdd(&cnt[(entries0[p] >> 17) & (NPB - 1)], 1);
    __syncthreads();
    if (t < NPB) scn[t] = cnt[t];
    __syncthreads();
    for (int s = 1; s < NPB; s <<= 1) {
        int u = 0;
        if (t < NPB && t >= s) u = scn[t - s];
        __syncthreads();
        if (t < NPB) scn[t] += u;
        __syncthreads();
    }
    if (t < NPB) {
        int node = b * NPB + t;
        int c = cnt[t];
        int o = *shb + scn[t] - c;     // exclusive prefix in compact space
        cur[t] = o;
        if (node < N) {
            off[node]  = o;
            deg[node]  = c;
            dinv[node] = rsqrtf((float)c + 1.0f);
        }
    }
    __syncthreads();
    for (int p = s0 + t; p < s1; p += 256) {
        int e = entries0[p];
        int pos = atomicAdd(&cur[(e >> 17) & (NPB - 1)], 1);
        entries1[pos] = e & 0x1FFFF;   // src only (4B)
    }
}

// --- gemm body: H(fp16) = (X @ W^T) [* scale(row)], 64x64 tile, 4x4 reg ----
template <typename InT>
__device__ __forceinline__ void gemm_body(const InT* __restrict__ X,
                                          const float* __restrict__ W,
                                          const float* __restrict__ scale,
                                          __half* __restrict__ H, int N, int bx,
                                          float* xt, float* wt) {
    const int t = threadIdx.x;
    const int i0 = bx * 64;
#pragma unroll
    for (int r = 0; r < 16; ++r) {
        int idx = r * 256 + t;
        int j = idx >> 6, k = idx & 63;
        wt[k * 68 + j] = W[idx];
    }
#pragma unroll
    for (int r = 0; r < 16; ++r) {
        int idx = r * 256 + t;
        int i = idx >> 6, k = idx & 63;
        float v = 0.0f;
        if (i0 + i < N) {
            if constexpr (sizeof(InT) == 2)
                v = __half2float(((const __half*)X)[(size_t)(i0 + i) * D + k]);
            else
                v = ((const float*)X)[(size_t)(i0 + i) * D + k];
        }
        xt[k * 68 + i] = v;
    }
    __syncthreads();
    const int tn = (t & 15) * 4;
    const int tc = (t >> 4) * 4;
    float acc[4][4] = {};
#pragma unroll 8
    for (int k = 0; k < 64; ++k) {
        const float4 xa = *(const float4*)(xt + k * 68 + tn);
        const float4 wb = *(const float4*)(wt + k * 68 + tc);
        acc[0][0] += xa.x * wb.x; acc[0][1] += xa.x * wb.y; acc[0][2] += xa.x * wb.z; acc[0][3] += xa.x * wb.w;
        acc[1][0] += xa.y * wb.x; acc[1][1] += xa.y * wb.y; acc[1][2] += xa.y * wb.z; acc[1][3] += xa.y * wb.w;
        acc[2][0] += xa.z * wb.x; acc[2][1] += xa.z * wb.y; acc[2][2] += xa.z * wb.z; acc[2][3] += xa.z * wb.w;
        acc[3][0] += xa.w * wb.x; acc[3][1] += xa.w * wb.y; acc[3][2] += xa.w * wb.z; acc[3][3] += xa.w * wb.w;
    }
#pragma unroll
    for (int a = 0; a < 4; ++a) {
        int i = i0 + tn + a;
        if (i < N) {
            float sc = scale ? scale[i] : 1.0f;
            union { __half2 h2[2]; uint2 u2; } pk;
            pk.h2[0].x = __float2half_rn(acc[a][0] * sc);
            pk.h2[0].y = __float2half_rn(acc[a][1] * sc);
            pk.h2[1].x = __float2half_rn(acc[a][2] * sc);
            pk.h2[1].y = __float2half_rn(acc[a][3] * sc);
            *(uint2*)(&H[(size_t)i * D + tc]) = pk.u2;
        }
    }
}

// --- merged: regroup (blocks [0,B)) || gemm1 (blocks [B, B+tiles)) ---------
__global__ __launch_bounds__(256) void regroup_gemm1(const int* __restrict__ entries0,
                                                     const int* __restrict__ btot,
                                                     int* __restrict__ off,
                                                     int* __restrict__ deg,
                                                     float* __restrict__ dinv,
                                                     int* __restrict__ entries1,
                                                     int* __restrict__ cursor,
                                                     int N, int B,
                                                     const float* __restrict__ X,
                                                     const float* __restrict__ W1,
                                                     __half* __restrict__ Hh) {
    __shared__ float xt[64 * 68];
    __shared__ float wt[64 * 68];
    if ((int)blockIdx.x < B) {
        int b = blockIdx.x;
        int* cnt = (int*)xt;           // alias regroup LDS into gemm's tiles
        int* scn = cnt + NPB;
        int* cur = scn + NPB;
        int* shb = cur + NPB;
        regroup_body(entries0, b * CAP, b * CAP + btot[b], off, deg, dinv,
                     entries1, cursor, N, b, cnt, scn, cur, shb);
    } else {
        gemm_body<float>(X, W1, nullptr, Hh, N, (int)blockIdx.x - B, xt, wt);
    }
}

// --- per-node aggregate inner body (identical memory pattern to r9/r10) ----
template <bool PRESCALED>
__device__ __forceinline__ float2 agg_node(const int* __restrict__ csr, int beg, int end,
                                           const __half2* __restrict__ H2,
                                           const float* __restrict__ dinv,
                                           float dd, int p2, int h) {
    float2 acc = make_float2(0.0f, 0.0f);
    int p = beg;
    for (; p + 16 <= end; p += 16) {       // 8 x 256B gathers in flight
        int s[8];
#pragma unroll
        for (int i = 0; i < 8; ++i) s[i] = csr[p + 2 * i + h];
        __half2 g[8];
#pragma unroll
        for (int i = 0; i < 8; ++i) g[i] = H2[(size_t)s[i] * 32 + p2];
        if constexpr (PRESCALED) {
#pragma unroll
            for (int i = 0; i < 8; ++i) {
                float2 f = __half22float2(g[i]);
                acc.x += f.x; acc.y += f.y;
            }
        } else {
            float dv[8];
#pragma unroll
            for (int i = 0; i < 8; ++i) dv[i] = dinv[s[i]];
#pragma unroll
            for (int i = 0; i < 8; ++i) {
                float2 f = __half22float2(g[i]);
                float c = dv[i] * dd;
                acc.x += f.x * c; acc.y += f.y * c;
            }
        }
    }
    for (; p + 8 <= end; p += 8) {
        int s0v = csr[p + 0 + h], s1v = csr[p + 2 + h];
        int s2v = csr[p + 4 + h], s3v = csr[p + 6 + h];
        __half2 g0 = H2[(size_t)s0v * 32 + p2];
        __half2 g1 = H2[(size_t)s1v * 32 + p2];
        __half2 g2 = H2[(size_t)s2v * 32 + p2];
        __half2 g3 = H2[(size_t)s3v * 32 + p2];
        float2 f0 = __half22float2(g0), f1 = __half22float2(g1);
        float2 f2 = __half22float2(g2), f3 = __half22float2(g3);
        if constexpr (PRESCALED) {
            acc.x += f0.x + f1.x + f2.x + f3.x;
            acc.y += f0.y + f1.y + f2.y + f3.y;
        } else {
            float c0 = dinv[s0v] * dd, c1 = dinv[s1v] * dd;
            float c2 = dinv[s2v] * dd, c3 = dinv[s3v] * dd;
            acc.x += f0.x * c0; acc.y += f0.y * c0;
            acc.x += f1.x * c1; acc.y += f1.y * c1;
            acc.x += f2.x * c2; acc.y += f2.y * c2;
            acc.x += f3.x * c3; acc.y += f3.y * c3;
        }
    }
    for (; p + 2 <= end; p += 2) {
        int s0v = csr[p + h];
        __half2 g0 = H2[(size_t)s0v * 32 + p2];
        float2 f0 = __half22float2(g0);
        if constexpr (PRESCALED) {
            acc.x += f0.x; acc.y += f0.y;
        } else {
            float c0 = dinv[s0v] * dd;
            acc.x += f0.x * c0; acc.y += f0.y * c0;
        }
    }
    if (p < end && h == 0) {
        int s0v = csr[p];
        __half2 g0 = H2[(size_t)s0v * 32 + p2];
        float2 f0 = __half22float2(g0);
        if constexpr (PRESCALED) {
            acc.x += f0.x; acc.y += f0.y;
        } else {
            float c0 = dinv[s0v] * dd;
            acc.x += f0.x * c0; acc.y += f0.y * c0;
        }
    }
    return acc;
}

// --- aggregate3: one wave per node (final layer-2 aggregate) ---------------
template <typename OutT, bool PRESCALED>
__global__ __launch_bounds__(256) void aggregate3(const int* __restrict__ csr,
                                                  const int* __restrict__ off,
                                                  const int* __restrict__ deg,
                                                  const float* __restrict__ dinv,
                                                  const __half* __restrict__ H,
                                                  const float* __restrict__ bias,
                                                  OutT* __restrict__ out, int N) {
    int node = blockIdx.x * 4 + (threadIdx.x >> 6);
    if (node >= N) return;
    int lane = threadIdx.x & 63;
    int p2 = lane & 31;
    int h  = lane >> 5;
    const __half2* H2 = (const __half2*)H;
    float dd = dinv[node];
    int beg = off[node];
    int end = beg + deg[node];
    float2 acc = agg_node<PRESCALED>(csr, beg, end, H2, dinv, dd, p2, h);
    acc.x += __shfl_xor(acc.x, 32);
    acc.y += __shfl_xor(acc.y, 32);
    if (h == 0) {
        float2 hs = __half22float2(H2[(size_t)node * 32 + p2]);
        float2 bv = ((const float2*)bias)[p2];
        float2 o;
        if constexpr (PRESCALED) {
            o.x = (acc.x + hs.x) * dd + bv.x;   // hs already has dinv[node]
            o.y = (acc.y + hs.y) * dd + bv.y;
        } else {
            float s = dd * dd;
            o.x = acc.x + bv.x + hs.x * s;
            o.y = acc.y + bv.y + hs.y * s;
        }
        if constexpr (sizeof(OutT) == 2) {
            ((__half2*)(out + (size_t)node * D))[p2] = __float22half2_rn(o);
        } else {
            ((float2*)(out + (size_t)node * D))[p2] = o;
        }
    }
}

// --- fused agg1+gemm2: block = 64 nodes; aggregate (+b1+self) -> xt (fp32),
//     then in-block GEMM x W2 with dinv row prescale -> H2 (fp16). ----------
__global__ __launch_bounds__(256) void agg1_gemm2(const int* __restrict__ csr,
                                                  const int* __restrict__ off,
                                                  const int* __restrict__ deg,
                                                  const float* __restrict__ dinv,
                                                  const __half* __restrict__ H1,
                                                  const float* __restrict__ b1,
                                                  const float* __restrict__ W2,
                                                  __half* __restrict__ H2out, int N) {
    __shared__ float xt[64 * 68];
    __shared__ float wt[64 * 68];
    const int t = threadIdx.x;
#pragma unroll
    for (int r = 0; r < 16; ++r) {         // W2 tile (read before first sync)
        int idx = r * 256 + t;
        int j = idx >> 6, k = idx & 63;
        wt[k * 68 + j] = W2[idx];
    }
    const int i0 = blockIdx.x * 64;
    const int w = t >> 6, lane = t & 63, p2 = lane & 31, h = lane >> 5;
    const __half2* H2 = (const __half2*)H1;
    float2 bv = ((const float2*)b1)[p2];
    for (int r = 0; r < 16; ++r) {
        int il = w * 16 + r;
        int node = i0 + il;
        if (node < N) {                     // wave-uniform branch
            float dd = dinv[node];
            int beg = off[node];
            int end = beg + deg[node];
            float2 acc = agg_node<false>(csr, beg, end, H2, dinv, dd, p2, h);
            acc.x += __shfl_xor(acc.x, 32);
            acc.y += __shfl_xor(acc.y, 32);
            if (h == 0) {
                float s = dd * dd;
                float2 hs = __half22float2(H2[(size_t)node * 32 + p2]);
                xt[(2 * p2)     * 68 + il] = acc.x + bv.x + hs.x * s;
                xt[(2 * p2 + 1) * 68 + il] = acc.y + bv.y + hs.y * s;
            }
        }
    }
    __syncthreads();
    const int tn = (t & 15) * 4;
    const int tc = (t >> 4) * 4;
    float acc[4][4] = {};
#pragma unroll 8
    for (int k = 0; k < 64; ++k) {
        const float4 xa = *(const float4*)(xt + k * 68 + tn);
        const float4 wb = *(const float4*)(wt + k * 68 + tc);
        acc[0][0] += xa.x * wb.x; acc[0][1] += xa.x * wb.y; acc[0][2] += xa.x * wb.z; acc[0][3] += xa.x * wb.w;
        acc[1][0] += xa.y * wb.x; acc[1][1] += xa.y * wb.y; acc[1][2] += xa.y * wb.z; acc[1][3] += xa.y * wb.w;
        acc[2][0] += xa.z * wb.x; acc[2][1] += xa.z * wb.y; acc[2][2] += xa.z * wb.z; acc[2][3] += xa.z * wb.w;
        acc[3][0] += xa.w * wb.x; acc[3][1] += xa.w * wb.y; acc[3][2] += xa.w * wb.z; acc[3][3] += xa.w * wb.w;
    }
#pragma unroll
    for (int a = 0; a < 4; ++a) {
        int i = i0 + tn + a;
        if (i < N) {
            float sc = dinv[i];             // prescale for agg2<PRESCALED>
            union { __half2 h2[2]; uint2 u2; } pk;
            pk.h2[0].x = __float2half_rn(acc[a][0] * sc);
            pk.h2[0].y = __float2half_rn(acc[a][1] * sc);
            pk.h2[1].x = __float2half_rn(acc[a][2] * sc);
            pk.h2[1].y = __float2half_rn(acc[a][3] * sc);
            *(uint2*)(&H2out[(size_t)i * D + tc]) = pk.u2;
        }
    }
}

// --- fallback (round-1 fp32 atomic path) kernels ---------------------------
__global__ __launch_bounds__(256) void deg_kernel(const int* __restrict__ dst,
                                                  int* __restrict__ deg, int nE) {
    int e = blockIdx.x * 256 + threadIdx.x;
    if (e < nE) atomicAdd(&deg[dst[e]], 1);
}

__global__ __launch_bounds__(256) void dinv_kernel(const int* __restrict__ deg,
                                                   float* __restrict__ dinv, int N) {
    int i = blockIdx.x * 256 + threadIdx.x;
    if (i < N) dinv[i] = rsqrtf((float)deg[i] + 1.0f);
}

__global__ __launch_bounds__(256) void gemm_xwt(const float* __restrict__ X,
                                                const float* __restrict__ W,
                                                float* __restrict__ H, int N) {
    __shared__ float xt[64 * 68];
    __shared__ float wt[64 * 68];
    const int t = threadIdx.x;
    const int i0 = blockIdx.x * 64;
#pragma unroll
    for (int r = 0; r < 16; ++r) {
        int idx = r * 256 + t;
        int j = idx >> 6, k = idx & 63;
        wt[k * 68 + j] = W[idx];
    }
#pragma unroll
    for (int r = 0; r < 16; ++r) {
        int idx = r * 256 + t;
        int i = idx >> 6, k = idx & 63;
        float v = 0.0f;
        if (i0 + i < N) v = X[(size_t)(i0 + i) * D + k];
        xt[k * 68 + i] = v;
    }
    __syncthreads();
    const int tn = (t & 15) * 4;
    const int tc = (t >> 4) * 4;
    float acc[4][4] = {};
#pragma unroll 8
    for (int k = 0; k < 64; ++k) {
        const float4 xa = *(const float4*)(xt + k * 68 + tn);
        const float4 wb = *(const float4*)(wt + k * 68 + tc);
        acc[0][0] += xa.x * wb.x; acc[0][1] += xa.x * wb.y; acc[0][2] += xa.x * wb.z; acc[0][3] += xa.x * wb.w;
        acc[1][0] += xa.y * wb.x; acc[1][1] += xa.y * wb.y; acc[1][2] += xa.y * wb.z; acc[1][3] += xa.y * wb.w;
        acc[2][0] += xa.z * wb.x; acc[2][1] += xa.z * wb.y; acc[2][2] += xa.z * wb.z; acc[2][3] += xa.z * wb.w;
        acc[3][0] += xa.w * wb.x; acc[3][1] += xa.w * wb.y; acc[3][2] += xa.w * wb.z; acc[3][3] += xa.w * wb.w;
    }
#pragma unroll
    for (int a = 0; a < 4; ++a) {
        int i = i0 + tn + a;
        if (i < N) {
            float4 o = make_float4(acc[a][0], acc[a][1], acc[a][2], acc[a][3]);
            *(float4*)(H + (size_t)i * D + tc) = o;
        }
    }
}

__global__ __launch_bounds__(256) void init_out(const float* __restrict__ H,
                                                const float* __restrict__ dinv,
                                                const float* __restrict__ b,
                                                float* __restrict__ out, int N) {
    int idx4 = blockIdx.x * 256 + threadIdx.x;
    if (idx4 >= N * 16) return;
    int i = idx4 >> 4;
    int jc = idx4 & 15;
    float di = dinv[i];
    float s = di * di;
    float4 h4 = ((const float4*)H)[idx4];
    float4 b4 = ((const float4*)b)[jc];
    ((float4*)out)[idx4] = make_float4(b4.x + h4.x * s, b4.y + h4.y * s,
                                       b4.z + h4.z * s, b4.w + h4.w * s);
}

__global__ __launch_bounds__(256) void edge_scatter(const int* __restrict__ src,
                                                    const int* __restrict__ dst,
                                                    const float* __restrict__ dinv,
                                                    const float* __restrict__ H,
                                                    float* __restrict__ out, int nE) {
    int tid = blockIdx.x * 256 + threadIdx.x;
    int e = tid >> 4;
    if (e >= nE) return;
    int l = tid & 15;
    int s = src[e];
    int d = dst[e];
    float c = dinv[s] * dinv[d];
    float4 v = ((const float4*)H)[s * 16 + l];
    float* o = out + (size_t)d * D + l * 4;
    unsafeAtomicAdd(o + 0, v.x * c);
    unsafeAtomicAdd(o + 1, v.y * c);
    unsafeAtomicAdd(o + 2, v.z * c);
    unsafeAtomicAdd(o + 3, v.w * c);
}

static inline size_t align_up(size_t v, size_t a) { return (v + a - 1) & ~(a - 1); }

extern "C" void kernel_launch(void* const* d_in, const int* in_sizes, int n_in,
                              void* d_out, int out_size, void* d_ws, size_t ws_size,
                              hipStream_t stream) {
    const float* x  = (const float*)d_in[0];
    const int*   ei = (const int*)d_in[1];
    const float* W1 = (const float*)d_in[2];
    const float* b1 = (const float*)d_in[3];
    const float* W2 = (const float*)d_in[4];
    const float* b2 = (const float*)d_in[5];
    float* out = (float*)d_out;

    const int N  = in_sizes[0] / D;   // 100000
    const int nE = in_sizes[1] / 2;   // 1600000
    const int* srcp = ei;
    const int* dstv = ei + nE;

    const int B = (N + NPB - 1) / NPB;      // 782
    const int C = (nE + CHUNK - 1) / CHUNK; // 391

    char* base_p = (char*)d_ws;

    int gb_n = (N + 255) / 256;
    int gb_g = (N + 63) / 64;
    int gb_e = (nE + 255) / 256;
    int gb_a = (N + 3) / 4;

    // --- tier-1 layout ---
    size_t o = 0;
    int* bcur   = (int*)(base_p + o);               // B ints + cursor (1 int)
    int* cursor = bcur + B;
    o = align_up(o + (size_t)(B + 1) * 4, 256);
    int* off    = (int*)(base_p + o);   o = align_up(o + (size_t)N * 4, 256);
    int* deg    = (int*)(base_p + o);   o = align_up(o + (size_t)N * 4, 256);
    float* dinv = (float*)(base_p + o); o = align_up(o + (size_t)N * 4, 256);
    int* entries1 = (int*)(base_p + o); o = align_up(o + (size_t)nE * 4, 256);
    // region: entries0 (MAXB*CAP*4 = 9.6MB) while building; H2 (N*D*2) after
    size_t rE0 = (size_t)MAXB * CAP * 4;
    size_t rH2 = (size_t)N * D * 2;
    size_t rX  = rE0 > rH2 ? rE0 : rH2;
    int* entries0 = (int*)(base_p + o);          // live: build_scatter..regroup
    __half* H2h   = (__half*)(base_p + o);       // live: agg1_gemm2..agg2
    o = align_up(o + rX, 256);
    __half* Hh    = (__half*)(base_p + o);
    size_t need1 = o + align_up((size_t)N * D * 2, 256);   // ~33.3 MB

    if (ws_size >= need1 && B <= MAXB - 2) {
        hipMemsetAsync(bcur, 0, (size_t)(B + 1) * 4, stream);  // bcur + cursor
        build_scatter<<<C, BT, 0, stream>>>(srcp, dstv, bcur, entries0, nE, B);
        regroup_gemm1<<<B + gb_g, 256, 0, stream>>>(entries0, bcur, off, deg,
                                                    dinv, entries1, cursor,
                                                    N, B, x, W1, Hh);
        agg1_gemm2<<<gb_g, 256, 0, stream>>>(entries1, off, deg, dinv, Hh, b1,
                                             W2, H2h, N);
        aggregate3<float, true><<<gb_a, 256, 0, stream>>>(entries1, off, deg, dinv,
                                                          H2h, b2, out, N);
    } else {
        // ---------------- fallback: round-1 atomic path ----------------
        size_t fo = 0;
        int* fdeg    = (int*)(base_p + fo);  fo = align_up(fo + (size_t)N * 4, 256);
        float* fdinv = (float*)(base_p + fo); fo = align_up(fo + (size_t)N * 4, 256);
        float* bufA  = (float*)(base_p + fo);
        hipMemsetAsync(fdeg, 0, (size_t)N * 4, stream);
        deg_kernel<<<gb_e, 256, 0, stream>>>(dstv, fdeg, nE);
        dinv_kernel<<<gb_n, 256, 0, stream>>>(fdeg, fdinv, N);
        int gb_i = (N * 16 + 255) / 256;
        int gb_e16 = (int)(((long long)nE * 16 + 255) / 256);
        gemm_xwt<<<gb_g, 256, 0, stream>>>(x, W1, bufA, N);
        init_out<<<gb_i, 256, 0, stream>>>(bufA, fdinv, b1, out, N);
        edge_scatter<<<gb_e16, 256, 0, stream>>>(srcp, dstv, fdinv, bufA, out, nE);
        gemm_xwt<<<gb_g, 256, 0, stream>>>(out, W2, bufA, N);
        init_out<<<gb_i, 256, 0, stream>>>(bufA, fdinv, b2, out, N);
        edge_scatter<<<gb_e16, 256, 0, stream>>>(srcp, dstv, fdinv, bufA, out, nE);
    }
}

// Round 4
// 274.488 us; speedup vs baseline: 1.0829x; 1.0829x over previous
//
#include <hip/hip_runtime.h>
#include <hip/hip_fp16.h>

// ---------------------------------------------------------------------------
// 2-layer GCN. Round 13 (= r12 build head + r10 tail; fusion reverted):
//  - r12 POST-MORTEM: agg1_gemm2 fusion = 106us vs 53.5+10 unfused. Counters:
//    hbm_gbps 945 vs 2233 (MLP collapse, not traffic), occupancy 32% vs 65%
//    (34.8KB LDS -> 4 blocks/CU; only 6252 waves), 2M LDS bank-conflict cyc.
//    The aggregate is a latency/MLP machine -- NEVER fuse it into big-LDS
//    few-wave blocks; 16-nodes-per-wave serialization halves in-flight
//    gathers -> BW halves. A1h round-trip (~12us) << MLP loss (~43us).
//  - aggregate fetch is AT compulsory-replication floor (90MB ~= 8 XCD x
//    12.8MB x 86.5% coverage); PRESCALED A/B flat -> fill-bound. Untouched.
//  - build head kept from r12: memset + build_scatter (fixed-CAP regions,
//    count->reserve->scatter, edges in regs) + regroup||gemm1 with compact
//    entries1 alloc via global cursor (sum btot == nE -> all pos < nE).
// Dispatches: memset + 5 (build_scatter, regroup||gemm1, agg1, gemm2, agg2).
// NEVER use cooperative grid.sync on this stack (r7: ~90us/sync).
// ---------------------------------------------------------------------------

#define D 64
#define NPB 128          // nodes per bucket (dst >> 7)
#define MAXB 784         // >= ceil(100000/128) = 782 (+2 spare overflow room)
#define CHUNK 4096       // edges per build chunk
#define BT 512           // threads for build_scatter
#define CAP 3072         // entry slots per bucket (expected 2046, sigma~45)

// --- build_scatter: count chunk -> reserve per-bucket region -> scatter ----
// Edges kept in registers; one global read of src/dst total.
__global__ __launch_bounds__(BT) void build_scatter(const int* __restrict__ src,
                                                    const int* __restrict__ dst,
                                                    int* __restrict__ bcur,
                                                    int* __restrict__ entries0,
                                                    int nE, int B) {
    __shared__ int hist[MAXB];
    __shared__ int curs[MAXB];
    const int t = threadIdx.x;
    const int c = blockIdx.x;
    for (int b = t; b < B; b += BT) hist[b] = 0;
    __syncthreads();
    int e0 = c * CHUNK;
    int sv[CHUNK / BT], dv[CHUNK / BT];
#pragma unroll
    for (int i = 0; i < CHUNK / BT; ++i) {
        int e = e0 + i * BT + t;
        sv[i] = 0; dv[i] = -1;
        if (e < nE) {
            sv[i] = src[e];
            dv[i] = dst[e];
            atomicAdd(&hist[dv[i] >> 7], 1);
        }
    }
    __syncthreads();
    for (int b = t; b < B; b += BT) {
        int cnt = hist[b];
        int base = 0;
        if (cnt > 0) base = atomicAdd(&bcur[b], cnt);
        curs[b] = b * CAP + base;
    }
    __syncthreads();
#pragma unroll
    for (int i = 0; i < CHUNK / BT; ++i) {
        if (dv[i] >= 0) {
            int b = dv[i] >> 7;
            int pos = atomicAdd(&curs[b], 1);
            entries0[pos] = sv[i] | ((dv[i] & (NPB - 1)) << 17);
        }
    }
}

// --- regroup body: count+scan -> COMPACT region alloc -> node-sorted src --
// entries0 segment is sparse [s0, s1); output region in entries1 is compact,
// reserved via global cursor (sum over buckets == nE -> all pos < nE).
__device__ __forceinline__ void regroup_body(const int* __restrict__ entries0,
                                             int s0, int s1,
                                             int* __restrict__ off,
                                             int* __restrict__ deg,
                                             float* __restrict__ dinv,
                                             int* __restrict__ entries1,
                                             int* __restrict__ cursor, int N, int b,
                                             int* cnt, int* scn, int* cur, int* shb) {
    int t = threadIdx.x;
    if (t < NPB) cnt[t] = 0;
    if (t == 0) *shb = atomicAdd(cursor, s1 - s0);   // compact bucket base
    __syncthreads();
    for (int p = s0 + t; p < s1; p += 256)
        atomicAdd(&cnt[(entries0[p] >> 17) & (NPB - 1)], 1);
    __syncthreads();
    if (t < NPB) scn[t] = cnt[t];
    __syncthreads();
    for (int s = 1; s < NPB; s <<= 1) {
        int u = 0;
        if (t < NPB && t >= s) u = scn[t - s];
        __syncthreads();
        if (t < NPB) scn[t] += u;
        __syncthreads();
    }
    if (t < NPB) {
        int node = b * NPB + t;
        int c = cnt[t];
        int o = *shb + scn[t] - c;     // exclusive prefix in compact space
        cur[t] = o;
        if (node < N) {
            off[node]  = o;
            deg[node]  = c;
            dinv[node] = rsqrtf((float)c + 1.0f);
        }
    }
    __syncthreads();
    for (int p = s0 + t; p < s1; p += 256) {
        int e = entries0[p];
        int pos = atomicAdd(&cur[(e >> 17) & (NPB - 1)], 1);
        entries1[pos] = e & 0x1FFFF;   // src only (4B)
    }
}

// --- gemm body: H(fp16) = (X @ W^T) [* scale(row)], 64x64 tile, 4x4 reg ----
template <typename InT>
__device__ __forceinline__ void gemm_body(const InT* __restrict__ X,
                                          const float* __restrict__ W,
                                          const float* __restrict__ scale,
                                          __half* __restrict__ H, int N, int bx,
                                          float* xt, float* wt) {
    const int t = threadIdx.x;
    const int i0 = bx * 64;
#pragma unroll
    for (int r = 0; r < 16; ++r) {
        int idx = r * 256 + t;
        int j = idx >> 6, k = idx & 63;
        wt[k * 68 + j] = W[idx];
    }
#pragma unroll
    for (int r = 0; r < 16; ++r) {
        int idx = r * 256 + t;
        int i = idx >> 6, k = idx & 63;
        float v = 0.0f;
        if (i0 + i < N) {
            if constexpr (sizeof(InT) == 2)
                v = __half2float(((const __half*)X)[(size_t)(i0 + i) * D + k]);
            else
                v = ((const float*)X)[(size_t)(i0 + i) * D + k];
        }
        xt[k * 68 + i] = v;
    }
    __syncthreads();
    const int tn = (t & 15) * 4;
    const int tc = (t >> 4) * 4;
    float acc[4][4] = {};
#pragma unroll 8
    for (int k = 0; k < 64; ++k) {
        const float4 xa = *(const float4*)(xt + k * 68 + tn);
        const float4 wb = *(const float4*)(wt + k * 68 + tc);
        acc[0][0] += xa.x * wb.x; acc[0][1] += xa.x * wb.y; acc[0][2] += xa.x * wb.z; acc[0][3] += xa.x * wb.w;
        acc[1][0] += xa.y * wb.x; acc[1][1] += xa.y * wb.y; acc[1][2] += xa.y * wb.z; acc[1][3] += xa.y * wb.w;
        acc[2][0] += xa.z * wb.x; acc[2][1] += xa.z * wb.y; acc[2][2] += xa.z * wb.z; acc[2][3] += xa.z * wb.w;
        acc[3][0] += xa.w * wb.x; acc[3][1] += xa.w * wb.y; acc[3][2] += xa.w * wb.z; acc[3][3] += xa.w * wb.w;
    }
#pragma unroll
    for (int a = 0; a < 4; ++a) {
        int i = i0 + tn + a;
        if (i < N) {
            float sc = scale ? scale[i] : 1.0f;
            union { __half2 h2[2]; uint2 u2; } pk;
            pk.h2[0].x = __float2half_rn(acc[a][0] * sc);
            pk.h2[0].y = __float2half_rn(acc[a][1] * sc);
            pk.h2[1].x = __float2half_rn(acc[a][2] * sc);
            pk.h2[1].y = __float2half_rn(acc[a][3] * sc);
            *(uint2*)(&H[(size_t)i * D + tc]) = pk.u2;
        }
    }
}

template <typename InT>
__global__ __launch_bounds__(256) void gemm_xwt_h(const InT* __restrict__ X,
                                                  const float* __restrict__ W,
                                                  const float* __restrict__ scale,
                                                  __half* __restrict__ H, int N) {
    __shared__ float xt[64 * 68];
    __shared__ float wt[64 * 68];
    gemm_body<InT>(X, W, scale, H, N, blockIdx.x, xt, wt);
}

// --- merged: regroup (blocks [0,B)) || gemm1 (blocks [B, B+tiles)) ---------
__global__ __launch_bounds__(256) void regroup_gemm1(const int* __restrict__ entries0,
                                                     const int* __restrict__ btot,
                                                     int* __restrict__ off,
                                                     int* __restrict__ deg,
                                                     float* __restrict__ dinv,
                                                     int* __restrict__ entries1,
                                                     int* __restrict__ cursor,
                                                     int N, int B,
                                                     const float* __restrict__ X,
                                                     const float* __restrict__ W1,
                                                     __half* __restrict__ Hh) {
    __shared__ float xt[64 * 68];
    __shared__ float wt[64 * 68];
    if ((int)blockIdx.x < B) {
        int b = blockIdx.x;
        int* cnt = (int*)xt;           // alias regroup LDS into gemm's tiles
        int* scn = cnt + NPB;
        int* cur = scn + NPB;
        int* shb = cur + NPB;
        regroup_body(entries0, b * CAP, b * CAP + btot[b], off, deg, dinv,
                     entries1, cursor, N, b, cnt, scn, cur, shb);
    } else {
        gemm_body<float>(X, W1, nullptr, Hh, N, (int)blockIdx.x - B, xt, wt);
    }
}

// --- per-node aggregate inner body (identical memory pattern since r9) -----
template <bool PRESCALED>
__device__ __forceinline__ float2 agg_node(const int* __restrict__ csr, int beg, int end,
                                           const __half2* __restrict__ H2,
                                           const float* __restrict__ dinv,
                                           float dd, int p2, int h) {
    float2 acc = make_float2(0.0f, 0.0f);
    int p = beg;
    for (; p + 16 <= end; p += 16) {       // 8 x 256B gathers in flight
        int s[8];
#pragma unroll
        for (int i = 0; i < 8; ++i) s[i] = csr[p + 2 * i + h];
        __half2 g[8];
#pragma unroll
        for (int i = 0; i < 8; ++i) g[i] = H2[(size_t)s[i] * 32 + p2];
        if constexpr (PRESCALED) {
#pragma unroll
            for (int i = 0; i < 8; ++i) {
                float2 f = __half22float2(g[i]);
                acc.x += f.x; acc.y += f.y;
            }
        } else {
            float dv[8];
#pragma unroll
            for (int i = 0; i < 8; ++i) dv[i] = dinv[s[i]];
#pragma unroll
            for (int i = 0; i < 8; ++i) {
                float2 f = __half22float2(g[i]);
                float c = dv[i] * dd;
                acc.x += f.x * c; acc.y += f.y * c;
            }
        }
    }
    for (; p + 8 <= end; p += 8) {
        int s0v = csr[p + 0 + h], s1v = csr[p + 2 + h];
        int s2v = csr[p + 4 + h], s3v = csr[p + 6 + h];
        __half2 g0 = H2[(size_t)s0v * 32 + p2];
        __half2 g1 = H2[(size_t)s1v * 32 + p2];
        __half2 g2 = H2[(size_t)s2v * 32 + p2];
        __half2 g3 = H2[(size_t)s3v * 32 + p2];
        float2 f0 = __half22float2(g0), f1 = __half22float2(g1);
        float2 f2 = __half22float2(g2), f3 = __half22float2(g3);
        if constexpr (PRESCALED) {
            acc.x += f0.x + f1.x + f2.x + f3.x;
            acc.y += f0.y + f1.y + f2.y + f3.y;
        } else {
            float c0 = dinv[s0v] * dd, c1 = dinv[s1v] * dd;
            float c2 = dinv[s2v] * dd, c3 = dinv[s3v] * dd;
            acc.x += f0.x * c0; acc.y += f0.y * c0;
            acc.x += f1.x * c1; acc.y += f1.y * c1;
            acc.x += f2.x * c2; acc.y += f2.y * c2;
            acc.x += f3.x * c3; acc.y += f3.y * c3;
        }
    }
    for (; p + 2 <= end; p += 2) {
        int s0v = csr[p + h];
        __half2 g0 = H2[(size_t)s0v * 32 + p2];
        float2 f0 = __half22float2(g0);
        if constexpr (PRESCALED) {
            acc.x += f0.x; acc.y += f0.y;
        } else {
            float c0 = dinv[s0v] * dd;
            acc.x += f0.x * c0; acc.y += f0.y * c0;
        }
    }
    if (p < end && h == 0) {
        int s0v = csr[p];
        __half2 g0 = H2[(size_t)s0v * 32 + p2];
        float2 f0 = __half22float2(g0);
        if constexpr (PRESCALED) {
            acc.x += f0.x; acc.y += f0.y;
        } else {
            float c0 = dinv[s0v] * dd;
            acc.x += f0.x * c0; acc.y += f0.y * c0;
        }
    }
    return acc;
}

// --- aggregate3: one wave per node -----------------------------------------
template <typename OutT, bool PRESCALED>
__global__ __launch_bounds__(256) void aggregate3(const int* __restrict__ csr,
                                                  const int* __restrict__ off,
                                                  const int* __restrict__ deg,
                                                  const float* __restrict__ dinv,
                                                  const __half* __restrict__ H,
                                                  const float* __restrict__ bias,
                                                  OutT* __restrict__ out, int N) {
    int node = blockIdx.x * 4 + (threadIdx.x >> 6);
    if (node >= N) return;
    int lane = threadIdx.x & 63;
    int p2 = lane & 31;
    int h  = lane >> 5;
    const __half2* H2 = (const __half2*)H;
    float dd = dinv[node];
    int beg = off[node];
    int end = beg + deg[node];
    float2 acc = agg_node<PRESCALED>(csr, beg, end, H2, dinv, dd, p2, h);
    acc.x += __shfl_xor(acc.x, 32);
    acc.y += __shfl_xor(acc.y, 32);
    if (h == 0) {
        float2 hs = __half22float2(H2[(size_t)node * 32 + p2]);
        float2 bv = ((const float2*)bias)[p2];
        float2 o;
        if constexpr (PRESCALED) {
            o.x = (acc.x + hs.x) * dd + bv.x;   // hs already has dinv[node]
            o.y = (acc.y + hs.y) * dd + bv.y;
        } else {
            float s = dd * dd;
            o.x = acc.x + bv.x + hs.x * s;
            o.y = acc.y + bv.y + hs.y * s;
        }
        if constexpr (sizeof(OutT) == 2) {
            ((__half2*)(out + (size_t)node * D))[p2] = __float22half2_rn(o);
        } else {
            ((float2*)(out + (size_t)node * D))[p2] = o;
        }
    }
}

// --- fallback (round-1 fp32 atomic path) kernels ---------------------------
__global__ __launch_bounds__(256) void deg_kernel(const int* __restrict__ dst,
                                                  int* __restrict__ deg, int nE) {
    int e = blockIdx.x * 256 + threadIdx.x;
    if (e < nE) atomicAdd(&deg[dst[e]], 1);
}

__global__ __launch_bounds__(256) void dinv_kernel(const int* __restrict__ deg,
                                                   float* __restrict__ dinv, int N) {
    int i = blockIdx.x * 256 + threadIdx.x;
    if (i < N) dinv[i] = rsqrtf((float)deg[i] + 1.0f);
}

__global__ __launch_bounds__(256) void gemm_xwt(const float* __restrict__ X,
                                                const float* __restrict__ W,
                                                float* __restrict__ H, int N) {
    __shared__ float xt[64 * 68];
    __shared__ float wt[64 * 68];
    const int t = threadIdx.x;
    const int i0 = blockIdx.x * 64;
#pragma unroll
    for (int r = 0; r < 16; ++r) {
        int idx = r * 256 + t;
        int j = idx >> 6, k = idx & 63;
        wt[k * 68 + j] = W[idx];
    }
#pragma unroll
    for (int r = 0; r < 16; ++r) {
        int idx = r * 256 + t;
        int i = idx >> 6, k = idx & 63;
        float v = 0.0f;
        if (i0 + i < N) v = X[(size_t)(i0 + i) * D + k];
        xt[k * 68 + i] = v;
    }
    __syncthreads();
    const int tn = (t & 15) * 4;
    const int tc = (t >> 4) * 4;
    float acc[4][4] = {};
#pragma unroll 8
    for (int k = 0; k < 64; ++k) {
        const float4 xa = *(const float4*)(xt + k * 68 + tn);
        const float4 wb = *(const float4*)(wt + k * 68 + tc);
        acc[0][0] += xa.x * wb.x; acc[0][1] += xa.x * wb.y; acc[0][2] += xa.x * wb.z; acc[0][3] += xa.x * wb.w;
        acc[1][0] += xa.y * wb.x; acc[1][1] += xa.y * wb.y; acc[1][2] += xa.y * wb.z; acc[1][3] += xa.y * wb.w;
        acc[2][0] += xa.z * wb.x; acc[2][1] += xa.z * wb.y; acc[2][2] += xa.z * wb.z; acc[2][3] += xa.z * wb.w;
        acc[3][0] += xa.w * wb.x; acc[3][1] += xa.w * wb.y; acc[3][2] += xa.w * wb.z; acc[3][3] += xa.w * wb.w;
    }
#pragma unroll
    for (int a = 0; a < 4; ++a) {
        int i = i0 + tn + a;
        if (i < N) {
            float4 o = make_float4(acc[a][0], acc[a][1], acc[a][2], acc[a][3]);
            *(float4*)(H + (size_t)i * D + tc) = o;
        }
    }
}

__global__ __launch_bounds__(256) void init_out(const float* __restrict__ H,
                                                const float* __restrict__ dinv,
                                                const float* __restrict__ b,
                                                float* __restrict__ out, int N) {
    int idx4 = blockIdx.x * 256 + threadIdx.x;
    if (idx4 >= N * 16) return;
    int i = idx4 >> 4;
    int jc = idx4 & 15;
    float di = dinv[i];
    float s = di * di;
    float4 h4 = ((const float4*)H)[idx4];
    float4 b4 = ((const float4*)b)[jc];
    ((float4*)out)[idx4] = make_float4(b4.x + h4.x * s, b4.y + h4.y * s,
                                       b4.z + h4.z * s, b4.w + h4.w * s);
}

__global__ __launch_bounds__(256) void edge_scatter(const int* __restrict__ src,
                                                    const int* __restrict__ dst,
                                                    const float* __restrict__ dinv,
                                                    const float* __restrict__ H,
                                                    float* __restrict__ out, int nE) {
    int tid = blockIdx.x * 256 + threadIdx.x;
    int e = tid >> 4;
    if (e >= nE) return;
    int l = tid & 15;
    int s = src[e];
    int d = dst[e];
    float c = dinv[s] * dinv[d];
    float4 v = ((const float4*)H)[s * 16 + l];
    float* o = out + (size_t)d * D + l * 4;
    unsafeAtomicAdd(o + 0, v.x * c);
    unsafeAtomicAdd(o + 1, v.y * c);
    unsafeAtomicAdd(o + 2, v.z * c);
    unsafeAtomicAdd(o + 3, v.w * c);
}

static inline size_t align_up(size_t v, size_t a) { return (v + a - 1) & ~(a - 1); }

extern "C" void kernel_launch(void* const* d_in, const int* in_sizes, int n_in,
                              void* d_out, int out_size, void* d_ws, size_t ws_size,
                              hipStream_t stream) {
    const float* x  = (const float*)d_in[0];
    const int*   ei = (const int*)d_in[1];
    const float* W1 = (const float*)d_in[2];
    const float* b1 = (const float*)d_in[3];
    const float* W2 = (const float*)d_in[4];
    const float* b2 = (const float*)d_in[5];
    float* out = (float*)d_out;

    const int N  = in_sizes[0] / D;   // 100000
    const int nE = in_sizes[1] / 2;   // 1600000
    const int* srcp = ei;
    const int* dstv = ei + nE;

    const int B = (N + NPB - 1) / NPB;      // 782
    const int C = (nE + CHUNK - 1) / CHUNK; // 391

    char* base_p = (char*)d_ws;

    int gb_n = (N + 255) / 256;
    int gb_g = (N + 63) / 64;
    int gb_e = (nE + 255) / 256;
    int gb_a = (N + 3) / 4;

    // --- tier-1 layout ---
    size_t o = 0;
    int* bcur   = (int*)(base_p + o);               // B ints + cursor (1 int)
    int* cursor = bcur + B;
    o = align_up(o + (size_t)(B + 1) * 4, 256);
    int* off    = (int*)(base_p + o);   o = align_up(o + (size_t)N * 4, 256);
    int* deg    = (int*)(base_p + o);   o = align_up(o + (size_t)N * 4, 256);
    float* dinv = (float*)(base_p + o); o = align_up(o + (size_t)N * 4, 256);
    int* entries1 = (int*)(base_p + o); o = align_up(o + (size_t)nE * 4, 256);
    // region X: entries0 (MAXB*CAP*4 = 9.6MB) while building; A1h (N*D*2)
    // after regroup (entries0 dead from then on).
    size_t rE0 = (size_t)MAXB * CAP * 4;
    size_t rA1 = (size_t)N * D * 2;
    size_t rX  = rE0 > rA1 ? rE0 : rA1;
    int* entries0 = (int*)(base_p + o);          // live: build_scatter..regroup
    __half* A1h   = (__half*)(base_p + o);       // live: agg1..gemm2
    o = align_up(o + rX, 256);
    __half* Hh    = (__half*)(base_p + o);       // H1, then overwritten by H2
    size_t need1 = o + align_up((size_t)N * D * 2, 256);   // ~33.3 MB

    if (ws_size >= need1 && B <= MAXB - 2) {
        hipMemsetAsync(bcur, 0, (size_t)(B + 1) * 4, stream);  // bcur + cursor
        build_scatter<<<C, BT, 0, stream>>>(srcp, dstv, bcur, entries0, nE, B);
        regroup_gemm1<<<B + gb_g, 256, 0, stream>>>(entries0, bcur, off, deg,
                                                    dinv, entries1, cursor,
                                                    N, B, x, W1, Hh);
        // agg1 (full-MLP standalone): Hh -> A1h (fp16, + b1 + self)
        aggregate3<__half, false><<<gb_a, 256, 0, stream>>>(entries1, off, deg, dinv,
                                                            Hh, b1, A1h, N);
        // gemm2: H2' = (A1 @ W2^T) * dinv[row] -> Hh (H1 dead)
        gemm_xwt_h<__half><<<gb_g, 256, 0, stream>>>(A1h, W2, dinv, Hh, N);
        // agg2 (prescaled): Hh -> out
        aggregate3<float, true><<<gb_a, 256, 0, stream>>>(entries1, off, deg, dinv,
                                                          Hh, b2, out, N);
    } else {
        // ---------------- fallback: round-1 atomic path ----------------
        size_t fo = 0;
        int* fdeg    = (int*)(base_p + fo);  fo = align_up(fo + (size_t)N * 4, 256);
        float* fdinv = (float*)(base_p + fo); fo = align_up(fo + (size_t)N * 4, 256);
        float* bufA  = (float*)(base_p + fo);
        hipMemsetAsync(fdeg, 0, (size_t)N * 4, stream);
        deg_kernel<<<gb_e, 256, 0, stream>>>(dstv, fdeg, nE);
        dinv_kernel<<<gb_n, 256, 0, stream>>>(fdeg, fdinv, N);
        int gb_i = (N * 16 + 255) / 256;
        int gb_e16 = (int)(((long long)nE * 16 + 255) / 256);
        gemm_xwt<<<gb_g, 256, 0, stream>>>(x, W1, bufA, N);
        init_out<<<gb_i, 256, 0, stream>>>(bufA, fdinv, b1, out, N);
        edge_scatter<<<gb_e16, 256, 0, stream>>>(srcp, dstv, fdinv, bufA, out, nE);
        gemm_xwt<<<gb_g, 256, 0, stream>>>(out, W2, bufA, N);
        init_out<<<gb_i, 256, 0, stream>>>(bufA, fdinv, b2, out, N);
        edge_scatter<<<gb_e16, 256, 0, stream>>>(srcp, dstv, fdinv, bufA, out, nE);
    }
}